// Round 3
// baseline (295430.469 us; speedup 1.0000x reference)
//
#include <hip/hip_runtime.h>
#include <hip/hip_bf16.h>

// 2-layer LSTM, B=64 T=2048 D=H=256. Device I/O is fp32 (matches reference
// dtypes; npz-size evidence). v3: weights RNE-converted once to packed bf16;
// xg = x@W_ih^T via bf16 MFMA (fp32->bf16 in-register); batch-parallel scan
// (64 WGs, fp32 h/c/accum, bf16 packed W_hh streamed from L2).

typedef unsigned short u16;
typedef unsigned int   u32;

typedef __attribute__((ext_vector_type(8))) short  short8;
typedef __attribute__((ext_vector_type(8))) float  float8;
typedef __attribute__((ext_vector_type(4))) float  f32x4;

#define B_  64
#define T_  2048
#define D_  256
#define H_  256
#define G_  1024   // 4*H

// ---- helpers ----
__device__ __forceinline__ u16 f2bf(float f) {          // RNE fp32->bf16
    u32 u = __float_as_uint(f);
    u32 r = u + 0x7fffu + ((u >> 16) & 1u);
    return (u16)(r >> 16);
}
__device__ __forceinline__ float bflo(u32 u) {
    union { u32 i; float f; } v; v.i = u << 16; return v.f;
}
__device__ __forceinline__ float bfhi(u32 u) {
    union { u32 i; float f; } v; v.i = u & 0xffff0000u; return v.f;
}
__device__ __forceinline__ float sigm(float x) {
    return 1.0f / (1.0f + __expf(-x));
}
__device__ __forceinline__ float tanh_(float x) {
    float e = __expf(-2.0f * fabsf(x));
    float r = (1.0f - e) / (1.0f + e);
    return x < 0.0f ? -r : r;
}

// ---- pack W_hh [1024][256] fp32 -> Wp[k2][j] = uint4{i,f,g,o} bf16-pairs --
// Wp[k2*256+j].x = pack(bf16(W[0*256+j][2k2]), bf16(W[0*256+j][2k2+1])) etc.
// 128 blocks exactly, no padding.
__global__ __launch_bounds__(256) void pack_whh(
    const float* __restrict__ W0, const float* __restrict__ W1,
    uint4* __restrict__ P0, uint4* __restrict__ P1)
{
    const int k2 = blockIdx.x;          // 0..127
    const int j  = threadIdx.x;         // 0..255
    const float* W = blockIdx.y ? W1 : W0;
    uint4*       P = blockIdx.y ? P1 : P0;
    uint4 v;
    u32* vp = &v.x;
#pragma unroll
    for (int g = 0; g < 4; ++g) {
        float2 w = *(const float2*)(W + (size_t)(g * 256 + j) * 256 + 2 * k2);
        vp[g] = (u32)f2bf(w.x) | ((u32)f2bf(w.y) << 16);
    }
    P[(size_t)k2 * 256 + j] = v;
}

// ---- xg GEMM: out[m][n] = sum_k A[trow(m)][k] * Bw[n][k] ----
// fp32 A,B converted to bf16 in-register, MFMA 16x16x32 accumulate fp32.
// m = b*Tc + tc (chunk-row); global A row = b*T_ + t0 + tc. Per-16-row
// fragment row mapping (valid for any power-of-2 Tc >= 16).
// WG tile 64x128, 4 waves, each wave 64x32.
template<int XBF>
__global__ __launch_bounds__(256) void gemm_xg(
    const float* __restrict__ A, const float* __restrict__ Bw,
    void* __restrict__ outv, int tclog2, int t0)
{
    const int tid = threadIdx.x;
    const int l  = tid & 63;
    const int w  = tid >> 6;
    const int m0 = blockIdx.x * 64;
    const int n0 = blockIdx.y * 128 + w * 32;
    const int rl = l & 15;
    const int kl = (l >> 4) * 8;
    const int tcmask = (1 << tclog2) - 1;

    const float* Ab[4];
#pragma unroll
    for (int mi = 0; mi < 4; ++mi) {
        int mbase = m0 + mi * 16;
        int b   = mbase >> tclog2;
        int tcb = mbase & tcmask;
        Ab[mi] = A + ((size_t)b * T_ + t0 + tcb) * D_;
    }

    f32x4 zz = {0.f, 0.f, 0.f, 0.f};
    f32x4 acc[4][2];
#pragma unroll
    for (int mi = 0; mi < 4; ++mi)
#pragma unroll
        for (int ni = 0; ni < 2; ++ni) acc[mi][ni] = zz;

#pragma unroll
    for (int ks = 0; ks < 8; ++ks) {
        const int k = ks * 32 + kl;
        short8 a[4], bb[2];
#pragma unroll
        for (int mi = 0; mi < 4; ++mi) {
            float8 af = *reinterpret_cast<const float8*>(Ab[mi] + (size_t)rl * D_ + k);
#pragma unroll
            for (int r = 0; r < 8; ++r) a[mi][r] = (short)f2bf(af[r]);
        }
#pragma unroll
        for (int ni = 0; ni < 2; ++ni) {
            float8 bf8 = *reinterpret_cast<const float8*>(
                Bw + (size_t)(n0 + ni * 16 + rl) * D_ + k);
#pragma unroll
            for (int r = 0; r < 8; ++r) bb[ni][r] = (short)f2bf(bf8[r]);
        }
#pragma unroll
        for (int mi = 0; mi < 4; ++mi)
#pragma unroll
            for (int ni = 0; ni < 2; ++ni)
                acc[mi][ni] = __builtin_amdgcn_mfma_f32_16x16x32_bf16(
                    a[mi], bb[ni], acc[mi][ni], 0, 0, 0);
    }

    // C/D layout: col = lane&15, row = (lane>>4)*4 + reg  [m89-verified]
    const int rr0 = (l >> 4) * 4;
    const int cc  = l & 15;
#pragma unroll
    for (int mi = 0; mi < 4; ++mi)
#pragma unroll
        for (int ni = 0; ni < 2; ++ni) {
            f32x4 d = acc[mi][ni];
            size_t mrow = (size_t)(m0 + mi * 16 + rr0);   // chunk-row m
            int col = n0 + ni * 16 + cc;
#pragma unroll
            for (int r = 0; r < 4; ++r) {
                size_t idx = (mrow + r) * G_ + col;
                if (XBF) ((u16*)outv)[idx] = f2bf(d[r]);
                else     ((float*)outv)[idx] = d[r];
            }
        }
}

// ---- sequential scan: one WG (512 thr) per batch element ----
// threads [0,256): hidden unit j, K-half 0; [256,512): same j, K-half 1.
// Partial gate sums reduced via LDS; h broadcast via LDS fp32; c in regs.
template<int XBF>
__global__ __launch_bounds__(512) void lstm_scan(
    const void* __restrict__ xgv,        // [B][Tc][1024] fp32 or bf16
    const uint4* __restrict__ Wp,        // [128][256] packed bf16 pairs
    const float* __restrict__ bias,      // [1024] fp32
    float* __restrict__ state,           // h[64][256], c[64][256] fp32
    float* __restrict__ h_out,           // [B][T_][H_] fp32
    float* __restrict__ hc_last,         // null unless final chunk of layer 2
    int Tc, int t0)
{
    const int b   = blockIdx.x;
    const int tid = threadIdx.x;
    const int j   = tid & 255;
    const int kh  = tid >> 8;

    __shared__ __align__(16) float h_sh[256];
    __shared__ __align__(16) float red[4][256];

    const float* xgf = (const float*)xgv;
    const u16*   xgb = (const u16*)xgv;

    float h = 0.f, c = 0.f;
    float bi = 0.f, bf = 0.f, bg = 0.f, bo = 0.f;
    size_t xo = (size_t)b * Tc * G_ + j;
    float nx0 = 0.f, nx1 = 0.f, nx2 = 0.f, nx3 = 0.f;

    if (kh == 0) {
        if (t0) {
            h = state[b * H_ + j];
            c = state[B_ * H_ + b * H_ + j];
        }
        bi = bias[j];
        bf = bias[256 + j];
        bg = bias[512 + j];
        bo = bias[768 + j];
        h_sh[j] = h;
        if (XBF) {
            nx0 = bflo((u32)xgb[xo] << 0) ;  // bf16 -> f32
            nx0 = bflo((u32)xgb[xo]);
            nx1 = bflo((u32)xgb[xo + 256]);
            nx2 = bflo((u32)xgb[xo + 512]);
            nx3 = bflo((u32)xgb[xo + 768]);
        } else {
            nx0 = xgf[xo]; nx1 = xgf[xo + 256];
            nx2 = xgf[xo + 512]; nx3 = xgf[xo + 768];
        }
    }
    const uint4* wpj = Wp + (size_t)kh * 64 * 256 + j;
    __syncthreads();

    for (int t = 0; t < Tc; ++t) {
        float a0, a1, a2, a3;
        if (kh == 0) {
            a0 = nx0 + bi; a1 = nx1 + bf; a2 = nx2 + bg; a3 = nx3 + bo;
            // prefetch next step's xg (clamped at the final step: reloads
            // the current, valid row; values discarded after loop exit)
            if (t + 1 < Tc) xo += G_;
            if (XBF) {
                nx0 = bflo((u32)xgb[xo]);
                nx1 = bflo((u32)xgb[xo + 256]);
                nx2 = bflo((u32)xgb[xo + 512]);
                nx3 = bflo((u32)xgb[xo + 768]);
            } else {
                nx0 = xgf[xo]; nx1 = xgf[xo + 256];
                nx2 = xgf[xo + 512]; nx3 = xgf[xo + 768];
            }
        } else {
            a0 = a1 = a2 = a3 = 0.f;
        }

        uint4 wreg[16];
#pragma unroll
        for (int p = 0; p < 16; ++p) wreg[p] = wpj[(size_t)p * 256];

#pragma unroll
        for (int kb = 0; kb < 64; kb += 16) {
#pragma unroll
            for (int p = 0; p < 16; ++p) {
                uint4 wv = wreg[p];
                if (kb < 48)                       // compile-time after unroll
                    wreg[p] = wpj[(size_t)(kb + 16 + p) * 256];
                float2 hv = *reinterpret_cast<const float2*>(
                    &h_sh[(kh * 64 + kb + p) * 2]);
                a0 += bflo(wv.x) * hv.x; a0 += bfhi(wv.x) * hv.y;
                a1 += bflo(wv.y) * hv.x; a1 += bfhi(wv.y) * hv.y;
                a2 += bflo(wv.z) * hv.x; a2 += bfhi(wv.z) * hv.y;
                a3 += bflo(wv.w) * hv.x; a3 += bfhi(wv.w) * hv.y;
            }
        }

        if (kh == 1) {
            red[0][j] = a0; red[1][j] = a1; red[2][j] = a2; red[3][j] = a3;
        }
        __syncthreads();   // h_sh reads done; red visible
        if (kh == 0) {
            a0 += red[0][j]; a1 += red[1][j]; a2 += red[2][j]; a3 += red[3][j];
            float i_ = sigm(a0);
            float f_ = sigm(a1);
            float g_ = tanh_(a2);
            float o_ = sigm(a3);
            c = f_ * c + i_ * g_;
            float hn = o_ * tanh_(c);
            h = hn;
            h_sh[j] = hn;
            h_out[((size_t)b * T_ + t0 + t) * H_ + j] = hn;
        }
        __syncthreads();   // new h visible
    }

    if (kh == 0) {
        state[b * H_ + j] = h;
        state[B_ * H_ + b * H_ + j] = c;
        if (hc_last) {
            hc_last[b * H_ + j] = h;
            hc_last[B_ * H_ + b * H_ + j] = c;
        }
    }
}

extern "C" void kernel_launch(void* const* d_in, const int* in_sizes, int n_in,
                              void* d_out, int out_size, void* d_ws, size_t ws_size,
                              hipStream_t stream)
{
    (void)in_sizes; (void)n_in; (void)out_size;

    const float* x    = (const float*)d_in[0];
    const float* Wih0 = (const float*)d_in[1];
    const float* Whh0 = (const float*)d_in[2];
    const float* b0   = (const float*)d_in[3];
    const float* Wih1 = (const float*)d_in[4];
    const float* Whh1 = (const float*)d_in[5];
    const float* b1   = (const float*)d_in[6];

    float* out   = (float*)d_out;
    float* hlast = out + (size_t)B_ * T_ * H_;

    // ws layout: Wp0 (128 blk), Wp1 (128 blk), state (h+c fp32), xg chunk
    char* ws = (char*)d_ws;
    const size_t WP_BYTES = (size_t)128 * 256 * 16;                 // 524288
    const size_t XG_OFF   = 2 * WP_BYTES + (size_t)2 * B_ * H_ * 4; // 1179648
    uint4* Wp0   = (uint4*)(ws);
    uint4* Wp1   = (uint4*)(ws + WP_BYTES);
    float* state = (float*)(ws + 2 * WP_BYTES);
    void*  xgbuf = (void*)(ws + XG_OFF);

    // Pick xg precision + chunk length that strictly fit ws_size.
    int Tc = -1, XB = 0;
    for (int tc = 2048; tc >= 16; tc >>= 1)
        if (XG_OFF + (size_t)B_ * tc * G_ * 4 <= ws_size) { Tc = tc; XB = 0; break; }
    if (Tc < 0)
        for (int tc = 2048; tc >= 16; tc >>= 1)
            if (XG_OFF + (size_t)B_ * tc * G_ * 2 <= ws_size) { Tc = tc; XB = 1; break; }
    if (Tc < 0) { Tc = 16; XB = 1; }   // ws hopeless; smallest footprint anyway
    int tclog2 = 31 - __builtin_clz((unsigned)Tc);
    int nch = T_ / Tc;

    pack_whh<<<dim3(128, 2), 256, 0, stream>>>(Whh0, Whh1, Wp0, Wp1);

    for (int L = 0; L < 2; ++L) {
        const float* Asrc = L ? (const float*)d_out : x;  // layer2 reads h1 from d_out
        const float* Wih  = L ? Wih1 : Wih0;
        const uint4* Wp   = L ? Wp1 : Wp0;
        const float* bias = L ? b1 : b0;
        for (int ci = 0; ci < nch; ++ci) {
            int t0 = ci * Tc;
            float* hc = (L == 1 && ci == nch - 1) ? hlast : (float*)nullptr;
            if (XB == 0) {
                gemm_xg<0><<<dim3((B_ * Tc) / 64, G_ / 128), 256, 0, stream>>>(
                    Asrc, Wih, xgbuf, tclog2, t0);
                lstm_scan<0><<<B_, 512, 0, stream>>>(
                    xgbuf, Wp, bias, state, out, hc, Tc, t0);
            } else {
                gemm_xg<1><<<dim3((B_ * Tc) / 64, G_ / 128), 256, 0, stream>>>(
                    Asrc, Wih, xgbuf, tclog2, t0);
                lstm_scan<1><<<B_, 512, 0, stream>>>(
                    xgbuf, Wp, bias, state, out, hc, Tc, t0);
            }
        }
    }
}

// Round 4
// 240005.713 us; speedup vs baseline: 1.2309x; 1.2309x over previous
//
#include <hip/hip_runtime.h>
#include <hip/hip_bf16.h>

// 2-layer LSTM, B=64 T=2048 D=H=256, fp32 I/O (confirmed round 3).
// v4: scan restructured to be register/LDS-resident for W_hh.
//   - 64 WGs x 256 threads, 1 wave/SIMD (__launch_bounds__(256,1)).
//   - thread j owns all 4 gates, full k=256 for hidden unit j.
//   - packed weights: 113 k2-blocks in VGPRs (452 regs) + 15 in LDS (61.4KB),
//     loaded ONCE before the t-loop. Zero per-step weight memory traffic.
//   - h broadcast via LDS fp32 (uniform-address reads = broadcast, free).
// Round-3 evidence: old scan was L1-miss-throughput bound (512KB/CU/step,
// VALUBusy 0.65%, 54us/step). This removes that traffic entirely.

typedef unsigned short u16;
typedef unsigned int   u32;

typedef __attribute__((ext_vector_type(8))) short  short8;
typedef __attribute__((ext_vector_type(8))) float  float8;
typedef __attribute__((ext_vector_type(4))) float  f32x4;

#define B_  64
#define T_  2048
#define D_  256
#define H_  256
#define G_  1024   // 4*H

#define NREG 113   // k2-blocks held in registers per thread
#define NLDS 15    // k2-blocks held in LDS (NREG+NLDS = 128)

// ---- helpers ----
__device__ __forceinline__ u16 f2bf(float f) {          // RNE fp32->bf16
    u32 u = __float_as_uint(f);
    u32 r = u + 0x7fffu + ((u >> 16) & 1u);
    return (u16)(r >> 16);
}
__device__ __forceinline__ float bflo(u32 u) {
    union { u32 i; float f; } v; v.i = u << 16; return v.f;
}
__device__ __forceinline__ float bfhi(u32 u) {
    union { u32 i; float f; } v; v.i = u & 0xffff0000u; return v.f;
}
__device__ __forceinline__ float sigm(float x) {
    return 1.0f / (1.0f + __expf(-x));
}
__device__ __forceinline__ float tanh_(float x) {
    float e = __expf(-2.0f * fabsf(x));
    float r = (1.0f - e) / (1.0f + e);
    return x < 0.0f ? -r : r;
}

// ---- pack W_hh [1024][256] fp32 -> Wp[k2][j] = uint4{i,f,g,o} bf16-pairs --
__global__ __launch_bounds__(256) void pack_whh(
    const float* __restrict__ W0, const float* __restrict__ W1,
    uint4* __restrict__ P0, uint4* __restrict__ P1)
{
    const int k2 = blockIdx.x;          // 0..127
    const int j  = threadIdx.x;         // 0..255
    const float* W = blockIdx.y ? W1 : W0;
    uint4*       P = blockIdx.y ? P1 : P0;
    uint4 v;
    u32* vp = &v.x;
#pragma unroll
    for (int g = 0; g < 4; ++g) {
        float2 w = *(const float2*)(W + (size_t)(g * 256 + j) * 256 + 2 * k2);
        vp[g] = (u32)f2bf(w.x) | ((u32)f2bf(w.y) << 16);
    }
    P[(size_t)k2 * 256 + j] = v;
}

// ---- xg GEMM: out[m][n] = sum_k A[trow(m)][k] * Bw[n][k] ----
// fp32 A,B converted to bf16 in-register, MFMA 16x16x32 accumulate fp32.
template<int XBF>
__global__ __launch_bounds__(256) void gemm_xg(
    const float* __restrict__ A, const float* __restrict__ Bw,
    void* __restrict__ outv, int tclog2, int t0)
{
    const int tid = threadIdx.x;
    const int l  = tid & 63;
    const int w  = tid >> 6;
    const int m0 = blockIdx.x * 64;
    const int n0 = blockIdx.y * 128 + w * 32;
    const int rl = l & 15;
    const int kl = (l >> 4) * 8;
    const int tcmask = (1 << tclog2) - 1;

    const float* Ab[4];
#pragma unroll
    for (int mi = 0; mi < 4; ++mi) {
        int mbase = m0 + mi * 16;
        int b   = mbase >> tclog2;
        int tcb = mbase & tcmask;
        Ab[mi] = A + ((size_t)b * T_ + t0 + tcb) * D_;
    }

    f32x4 zz = {0.f, 0.f, 0.f, 0.f};
    f32x4 acc[4][2];
#pragma unroll
    for (int mi = 0; mi < 4; ++mi)
#pragma unroll
        for (int ni = 0; ni < 2; ++ni) acc[mi][ni] = zz;

#pragma unroll
    for (int ks = 0; ks < 8; ++ks) {
        const int k = ks * 32 + kl;
        short8 a[4], bb[2];
#pragma unroll
        for (int mi = 0; mi < 4; ++mi) {
            float8 af = *reinterpret_cast<const float8*>(Ab[mi] + (size_t)rl * D_ + k);
#pragma unroll
            for (int r = 0; r < 8; ++r) a[mi][r] = (short)f2bf(af[r]);
        }
#pragma unroll
        for (int ni = 0; ni < 2; ++ni) {
            float8 bf8 = *reinterpret_cast<const float8*>(
                Bw + (size_t)(n0 + ni * 16 + rl) * D_ + k);
#pragma unroll
            for (int r = 0; r < 8; ++r) bb[ni][r] = (short)f2bf(bf8[r]);
        }
#pragma unroll
        for (int mi = 0; mi < 4; ++mi)
#pragma unroll
            for (int ni = 0; ni < 2; ++ni)
                acc[mi][ni] = __builtin_amdgcn_mfma_f32_16x16x32_bf16(
                    a[mi], bb[ni], acc[mi][ni], 0, 0, 0);
    }

    // C/D layout: col = lane&15, row = (lane>>4)*4 + reg  [m89-verified]
    const int rr0 = (l >> 4) * 4;
    const int cc  = l & 15;
#pragma unroll
    for (int mi = 0; mi < 4; ++mi)
#pragma unroll
        for (int ni = 0; ni < 2; ++ni) {
            f32x4 d = acc[mi][ni];
            size_t mrow = (size_t)(m0 + mi * 16 + rr0);
            int col = n0 + ni * 16 + cc;
#pragma unroll
            for (int r = 0; r < 4; ++r) {
                size_t idx = (mrow + r) * G_ + col;
                if (XBF) ((u16*)outv)[idx] = f2bf(d[r]);
                else     ((float*)outv)[idx] = d[r];
            }
        }
}

// ---- sequential scan v4: one WG (256 thr) per batch element ----
// Thread j: all 4 gates, full k. Weights resident in regs+LDS for the whole
// chunk. h broadcast via LDS fp32.
template<int XBF>
__global__ __launch_bounds__(256, 1) void lstm_scan(
    const void* __restrict__ xgv,        // [B][Tc][1024] fp32 or bf16
    const uint4* __restrict__ Wp,        // [128][256] packed bf16 pairs
    const float* __restrict__ bias,      // [1024] fp32
    float* __restrict__ state,           // h[64][256], c[64][256] fp32
    float* __restrict__ h_out,           // [B][T_][H_] fp32
    float* __restrict__ hc_last,         // null unless final chunk of layer 2
    int Tc, int t0)
{
    const int b = blockIdx.x;
    const int j = threadIdx.x;

    __shared__ __align__(16) uint4 wl[NLDS][256];   // 61440 B
    __shared__ __align__(16) float hf[256];         //  1024 B

    // ---- one-time weight residency setup ----
    uint4 wr[NREG];
#pragma unroll
    for (int p = 0; p < NREG; ++p)
        wr[p] = Wp[(size_t)p * 256 + j];
#pragma unroll
    for (int p = 0; p < NLDS; ++p)
        wl[p][j] = Wp[(size_t)(NREG + p) * 256 + j];

    float h = 0.f, c = 0.f;
    if (t0) {
        h = state[b * H_ + j];
        c = state[B_ * H_ + b * H_ + j];
    }
    const float bi = bias[j];
    const float bf_ = bias[256 + j];
    const float bg = bias[512 + j];
    const float bo = bias[768 + j];
    hf[j] = h;

    const float* xgf = (const float*)xgv;
    const u16*   xgb = (const u16*)xgv;
    size_t xo = (size_t)b * Tc * G_ + j;
    float nx0, nx1, nx2, nx3;
    if (XBF) {
        nx0 = bflo((u32)xgb[xo]);       nx1 = bflo((u32)xgb[xo + 256]);
        nx2 = bflo((u32)xgb[xo + 512]); nx3 = bflo((u32)xgb[xo + 768]);
    } else {
        nx0 = xgf[xo];       nx1 = xgf[xo + 256];
        nx2 = xgf[xo + 512]; nx3 = xgf[xo + 768];
    }
    float* hop = h_out + ((size_t)b * T_ + t0) * H_ + j;
    __syncthreads();

    for (int t = 0; t < Tc; ++t) {
        float a0 = nx0 + bi, a1 = nx1 + bf_, a2 = nx2 + bg, a3 = nx3 + bo;
        // prefetch next step's xg (clamped reload on final step)
        if (t + 1 < Tc) xo += G_;
        if (XBF) {
            nx0 = bflo((u32)xgb[xo]);       nx1 = bflo((u32)xgb[xo + 256]);
            nx2 = bflo((u32)xgb[xo + 512]); nx3 = bflo((u32)xgb[xo + 768]);
        } else {
            nx0 = xgf[xo];       nx1 = xgf[xo + 256];
            nx2 = xgf[xo + 512]; nx3 = xgf[xo + 768];
        }

        // dot: 113 k2 from registers
#pragma unroll
        for (int p = 0; p < NREG; ++p) {
            uint4 wv = wr[p];
            float2 hv = *reinterpret_cast<const float2*>(&hf[2 * p]);
            a0 += bflo(wv.x) * hv.x; a0 += bfhi(wv.x) * hv.y;
            a1 += bflo(wv.y) * hv.x; a1 += bfhi(wv.y) * hv.y;
            a2 += bflo(wv.z) * hv.x; a2 += bfhi(wv.z) * hv.y;
            a3 += bflo(wv.w) * hv.x; a3 += bfhi(wv.w) * hv.y;
        }
        // dot: 15 k2 from LDS
#pragma unroll
        for (int p = 0; p < NLDS; ++p) {
            uint4 wv = wl[p][j];
            float2 hv = *reinterpret_cast<const float2*>(&hf[2 * (NREG + p)]);
            a0 += bflo(wv.x) * hv.x; a0 += bfhi(wv.x) * hv.y;
            a1 += bflo(wv.y) * hv.x; a1 += bfhi(wv.y) * hv.y;
            a2 += bflo(wv.z) * hv.x; a2 += bfhi(wv.z) * hv.y;
            a3 += bflo(wv.w) * hv.x; a3 += bfhi(wv.w) * hv.y;
        }

        float i_ = sigm(a0);
        float f_ = sigm(a1);
        float g_ = tanh_(a2);
        float o_ = sigm(a3);
        c = f_ * c + i_ * g_;
        float hn = o_ * tanh_(c);
        h = hn;
        hop[0] = hn;
        hop += H_;

        __syncthreads();   // all hf reads of this step done
        hf[j] = hn;
        __syncthreads();   // new h visible
    }

    state[b * H_ + j] = h;
    state[B_ * H_ + b * H_ + j] = c;
    if (hc_last) {
        hc_last[b * H_ + j] = h;
        hc_last[B_ * H_ + b * H_ + j] = c;
    }
}

extern "C" void kernel_launch(void* const* d_in, const int* in_sizes, int n_in,
                              void* d_out, int out_size, void* d_ws, size_t ws_size,
                              hipStream_t stream)
{
    (void)in_sizes; (void)n_in; (void)out_size;

    const float* x    = (const float*)d_in[0];
    const float* Wih0 = (const float*)d_in[1];
    const float* Whh0 = (const float*)d_in[2];
    const float* b0   = (const float*)d_in[3];
    const float* Wih1 = (const float*)d_in[4];
    const float* Whh1 = (const float*)d_in[5];
    const float* b1   = (const float*)d_in[6];

    float* out   = (float*)d_out;
    float* hlast = out + (size_t)B_ * T_ * H_;

    // ws layout: Wp0 (128 blk), Wp1 (128 blk), state (h+c fp32), xg chunk
    char* ws = (char*)d_ws;
    const size_t WP_BYTES = (size_t)128 * 256 * 16;                 // 524288
    const size_t XG_OFF   = 2 * WP_BYTES + (size_t)2 * B_ * H_ * 4; // 1179648
    uint4* Wp0   = (uint4*)(ws);
    uint4* Wp1   = (uint4*)(ws + WP_BYTES);
    float* state = (float*)(ws + 2 * WP_BYTES);
    void*  xgbuf = (void*)(ws + XG_OFF);

    // Pick xg precision + chunk length that strictly fit ws_size.
    int Tc = -1, XB = 0;
    for (int tc = 2048; tc >= 16; tc >>= 1)
        if (XG_OFF + (size_t)B_ * tc * G_ * 4 <= ws_size) { Tc = tc; XB = 0; break; }
    if (Tc < 0)
        for (int tc = 2048; tc >= 16; tc >>= 1)
            if (XG_OFF + (size_t)B_ * tc * G_ * 2 <= ws_size) { Tc = tc; XB = 1; break; }
    if (Tc < 0) { Tc = 16; XB = 1; }
    int tclog2 = 31 - __builtin_clz((unsigned)Tc);
    int nch = T_ / Tc;

    pack_whh<<<dim3(128, 2), 256, 0, stream>>>(Whh0, Whh1, Wp0, Wp1);

    for (int L = 0; L < 2; ++L) {
        const float* Asrc = L ? (const float*)d_out : x;
        const float* Wih  = L ? Wih1 : Wih0;
        const uint4* Wp   = L ? Wp1 : Wp0;
        const float* bias = L ? b1 : b0;
        for (int ci = 0; ci < nch; ++ci) {
            int t0 = ci * Tc;
            float* hc = (L == 1 && ci == nch - 1) ? hlast : (float*)nullptr;
            if (XB == 0) {
                gemm_xg<0><<<dim3((B_ * Tc) / 64, G_ / 128), 256, 0, stream>>>(
                    Asrc, Wih, xgbuf, tclog2, t0);
                lstm_scan<0><<<B_, 256, 0, stream>>>(
                    xgbuf, Wp, bias, state, out, hc, Tc, t0);
            } else {
                gemm_xg<1><<<dim3((B_ * Tc) / 64, G_ / 128), 256, 0, stream>>>(
                    Asrc, Wih, xgbuf, tclog2, t0);
                lstm_scan<1><<<B_, 256, 0, stream>>>(
                    xgbuf, Wp, bias, state, out, hc, Tc, t0);
            }
        }
    }
}

// Round 5
// 84752.423 us; speedup vs baseline: 3.4858x; 2.8318x over previous
//
#include <hip/hip_runtime.h>
#include <hip/hip_bf16.h>

// 2-layer LSTM, B=64 T=2048 D=H=256, fp32 I/O.
// v5: TRUE full weight residency in the scan.
//   Round-4 evidence: VGPR_Count=256 (arch VGPRs cap at v0-v255 on gfx950);
//   compiler spilled ~60 weight blocks to scratch -> 256KB/CU/step reload
//   -> 43us/step latency-bound (VALUBusy 1.1%). Fix: explicit AGPR storage
//   via v_accvgpr_write/read inline asm ("a" constraints).
//   Per thread: 50 blocks VGPR (200 regs) + 63 blocks AGPR (252 regs)
//   + 15 blocks LDS (61KB). All 128 k2-blocks resident, zero per-step
//   weight memory traffic. h broadcast via LDS fp32.

typedef unsigned short u16;
typedef unsigned int   u32;

typedef __attribute__((ext_vector_type(8))) short  short8;
typedef __attribute__((ext_vector_type(8))) float  float8;
typedef __attribute__((ext_vector_type(4))) float  f32x4;

#define B_  64
#define T_  2048
#define D_  256
#define H_  256
#define G_  1024   // 4*H

#define NREG 50    // k2-blocks in VGPRs
#define NAG  63    // k2-blocks in AGPRs (explicit asm)
#define NLDS 15    // k2-blocks in LDS   (NREG+NAG+NLDS = 128)

#define AG_W(agv, src) asm("v_accvgpr_write_b32 %0, %1" : "=a"(agv) : "v"(src))
#define AG_R(dst, agv) asm("v_accvgpr_read_b32 %0, %1" : "=v"(dst) : "a"(agv))

// ---- helpers ----
__device__ __forceinline__ u16 f2bf(float f) {          // RNE fp32->bf16
    u32 u = __float_as_uint(f);
    u32 r = u + 0x7fffu + ((u >> 16) & 1u);
    return (u16)(r >> 16);
}
__device__ __forceinline__ float bflo(u32 u) {
    union { u32 i; float f; } v; v.i = u << 16; return v.f;
}
__device__ __forceinline__ float bfhi(u32 u) {
    union { u32 i; float f; } v; v.i = u & 0xffff0000u; return v.f;
}
__device__ __forceinline__ float sigm(float x) {
    return 1.0f / (1.0f + __expf(-x));
}
__device__ __forceinline__ float tanh_(float x) {
    float e = __expf(-2.0f * fabsf(x));
    float r = (1.0f - e) / (1.0f + e);
    return x < 0.0f ? -r : r;
}

// ---- pack W_hh [1024][256] fp32 -> Wp[k2][j] = uint4{i,f,g,o} bf16-pairs --
__global__ __launch_bounds__(256) void pack_whh(
    const float* __restrict__ W0, const float* __restrict__ W1,
    uint4* __restrict__ P0, uint4* __restrict__ P1)
{
    const int k2 = blockIdx.x;          // 0..127
    const int j  = threadIdx.x;         // 0..255
    const float* W = blockIdx.y ? W1 : W0;
    uint4*       P = blockIdx.y ? P1 : P0;
    uint4 v;
    u32* vp = &v.x;
#pragma unroll
    for (int g = 0; g < 4; ++g) {
        float2 w = *(const float2*)(W + (size_t)(g * 256 + j) * 256 + 2 * k2);
        vp[g] = (u32)f2bf(w.x) | ((u32)f2bf(w.y) << 16);
    }
    P[(size_t)k2 * 256 + j] = v;
}

// ---- xg GEMM: out[m][n] = sum_k A[trow(m)][k] * Bw[n][k] ----
// fp32 A,B converted to bf16 in-register, MFMA 16x16x32 accumulate fp32.
template<int XBF>
__global__ __launch_bounds__(256) void gemm_xg(
    const float* __restrict__ A, const float* __restrict__ Bw,
    void* __restrict__ outv, int tclog2, int t0)
{
    const int tid = threadIdx.x;
    const int l  = tid & 63;
    const int w  = tid >> 6;
    const int m0 = blockIdx.x * 64;
    const int n0 = blockIdx.y * 128 + w * 32;
    const int rl = l & 15;
    const int kl = (l >> 4) * 8;
    const int tcmask = (1 << tclog2) - 1;

    const float* Ab[4];
#pragma unroll
    for (int mi = 0; mi < 4; ++mi) {
        int mbase = m0 + mi * 16;
        int b   = mbase >> tclog2;
        int tcb = mbase & tcmask;
        Ab[mi] = A + ((size_t)b * T_ + t0 + tcb) * D_;
    }

    f32x4 zz = {0.f, 0.f, 0.f, 0.f};
    f32x4 acc[4][2];
#pragma unroll
    for (int mi = 0; mi < 4; ++mi)
#pragma unroll
        for (int ni = 0; ni < 2; ++ni) acc[mi][ni] = zz;

#pragma unroll
    for (int ks = 0; ks < 8; ++ks) {
        const int k = ks * 32 + kl;
        short8 a[4], bb[2];
#pragma unroll
        for (int mi = 0; mi < 4; ++mi) {
            float8 af = *reinterpret_cast<const float8*>(Ab[mi] + (size_t)rl * D_ + k);
#pragma unroll
            for (int r = 0; r < 8; ++r) a[mi][r] = (short)f2bf(af[r]);
        }
#pragma unroll
        for (int ni = 0; ni < 2; ++ni) {
            float8 bf8 = *reinterpret_cast<const float8*>(
                Bw + (size_t)(n0 + ni * 16 + rl) * D_ + k);
#pragma unroll
            for (int r = 0; r < 8; ++r) bb[ni][r] = (short)f2bf(bf8[r]);
        }
#pragma unroll
        for (int mi = 0; mi < 4; ++mi)
#pragma unroll
            for (int ni = 0; ni < 2; ++ni)
                acc[mi][ni] = __builtin_amdgcn_mfma_f32_16x16x32_bf16(
                    a[mi], bb[ni], acc[mi][ni], 0, 0, 0);
    }

    // C/D layout: col = lane&15, row = (lane>>4)*4 + reg  [m89-verified]
    const int rr0 = (l >> 4) * 4;
    const int cc  = l & 15;
#pragma unroll
    for (int mi = 0; mi < 4; ++mi)
#pragma unroll
        for (int ni = 0; ni < 2; ++ni) {
            f32x4 d = acc[mi][ni];
            size_t mrow = (size_t)(m0 + mi * 16 + rr0);
            int col = n0 + ni * 16 + cc;
#pragma unroll
            for (int r = 0; r < 4; ++r) {
                size_t idx = (mrow + r) * G_ + col;
                if (XBF) ((u16*)outv)[idx] = f2bf(d[r]);
                else     ((float*)outv)[idx] = d[r];
            }
        }
}

// ---- sequential scan v5: one WG (256 thr) per batch element ----
// Thread j: all 4 gates, full k=256 for hidden unit j. Weights fully
// resident: VGPR(50) + AGPR(63, explicit asm) + LDS(15) blocks.
template<int XBF>
__global__ __launch_bounds__(256, 1) void lstm_scan(
    const void* __restrict__ xgv,        // [B][Tc][1024] fp32 or bf16
    const uint4* __restrict__ Wp,        // [128][256] packed bf16 pairs
    const float* __restrict__ bias,      // [1024] fp32
    float* __restrict__ state,           // h[64][256], c[64][256] fp32
    float* __restrict__ h_out,           // [B][T_][H_] fp32
    float* __restrict__ hc_last,         // null unless final chunk of layer 2
    int Tc, int t0)
{
    const int b = blockIdx.x;
    const int j = threadIdx.x;

    __shared__ __align__(16) uint4 wl[NLDS][256];   // 61440 B
    __shared__ __align__(16) float hf[256];         //  1024 B

    // ---- one-time weight residency setup ----
    uint4 wr[NREG];
#pragma unroll
    for (int p = 0; p < NREG; ++p)
        wr[p] = Wp[(size_t)p * 256 + j];

    u32 ag[4 * NAG];                     // values pinned to AGPRs via asm
#pragma unroll
    for (int q = 0; q < NAG; ++q) {
        uint4 wv = Wp[(size_t)(NREG + q) * 256 + j];
        AG_W(ag[4 * q + 0], wv.x);
        AG_W(ag[4 * q + 1], wv.y);
        AG_W(ag[4 * q + 2], wv.z);
        AG_W(ag[4 * q + 3], wv.w);
    }
#pragma unroll
    for (int p = 0; p < NLDS; ++p)
        wl[p][j] = Wp[(size_t)(NREG + NAG + p) * 256 + j];

    float h = 0.f, c = 0.f;
    if (t0) {
        h = state[b * H_ + j];
        c = state[B_ * H_ + b * H_ + j];
    }
    const float bi  = bias[j];
    const float bf_ = bias[256 + j];
    const float bg  = bias[512 + j];
    const float bo  = bias[768 + j];
    hf[j] = h;

    const float* xgf = (const float*)xgv;
    const u16*   xgb = (const u16*)xgv;
    size_t xo = (size_t)b * Tc * G_ + j;
    float nx0, nx1, nx2, nx3;
    if (XBF) {
        nx0 = bflo((u32)xgb[xo]);       nx1 = bflo((u32)xgb[xo + 256]);
        nx2 = bflo((u32)xgb[xo + 512]); nx3 = bflo((u32)xgb[xo + 768]);
    } else {
        nx0 = __builtin_nontemporal_load(xgf + xo);
        nx1 = __builtin_nontemporal_load(xgf + xo + 256);
        nx2 = __builtin_nontemporal_load(xgf + xo + 512);
        nx3 = __builtin_nontemporal_load(xgf + xo + 768);
    }
    float* hop = h_out + ((size_t)b * T_ + t0) * H_ + j;
    __syncthreads();

    for (int t = 0; t < Tc; ++t) {
        float a0 = nx0 + bi, a1 = nx1 + bf_, a2 = nx2 + bg, a3 = nx3 + bo;
        // prefetch next step's xg (clamped reload on final step)
        if (t + 1 < Tc) xo += G_;
        if (XBF) {
            nx0 = bflo((u32)xgb[xo]);       nx1 = bflo((u32)xgb[xo + 256]);
            nx2 = bflo((u32)xgb[xo + 512]); nx3 = bflo((u32)xgb[xo + 768]);
        } else {
            nx0 = __builtin_nontemporal_load(xgf + xo);
            nx1 = __builtin_nontemporal_load(xgf + xo + 256);
            nx2 = __builtin_nontemporal_load(xgf + xo + 512);
            nx3 = __builtin_nontemporal_load(xgf + xo + 768);
        }

        // dot: 50 k2 from VGPRs
#pragma unroll
        for (int p = 0; p < NREG; ++p) {
            uint4 wv = wr[p];
            float2 hv = *reinterpret_cast<const float2*>(&hf[2 * p]);
            a0 += bflo(wv.x) * hv.x; a0 += bfhi(wv.x) * hv.y;
            a1 += bflo(wv.y) * hv.x; a1 += bfhi(wv.y) * hv.y;
            a2 += bflo(wv.z) * hv.x; a2 += bfhi(wv.z) * hv.y;
            a3 += bflo(wv.w) * hv.x; a3 += bfhi(wv.w) * hv.y;
        }
        // dot: 63 k2 from AGPRs
#pragma unroll
        for (int q = 0; q < NAG; ++q) {
            u32 wx, wy, wz, ww;
            AG_R(wx, ag[4 * q + 0]);
            AG_R(wy, ag[4 * q + 1]);
            AG_R(wz, ag[4 * q + 2]);
            AG_R(ww, ag[4 * q + 3]);
            float2 hv = *reinterpret_cast<const float2*>(&hf[2 * (NREG + q)]);
            a0 += bflo(wx) * hv.x; a0 += bfhi(wx) * hv.y;
            a1 += bflo(wy) * hv.x; a1 += bfhi(wy) * hv.y;
            a2 += bflo(wz) * hv.x; a2 += bfhi(wz) * hv.y;
            a3 += bflo(ww) * hv.x; a3 += bfhi(ww) * hv.y;
        }
        // dot: 15 k2 from LDS
#pragma unroll
        for (int p = 0; p < NLDS; ++p) {
            uint4 wv = wl[p][j];
            float2 hv = *reinterpret_cast<const float2*>(&hf[2 * (NREG + NAG + p)]);
            a0 += bflo(wv.x) * hv.x; a0 += bfhi(wv.x) * hv.y;
            a1 += bflo(wv.y) * hv.x; a1 += bfhi(wv.y) * hv.y;
            a2 += bflo(wv.z) * hv.x; a2 += bfhi(wv.z) * hv.y;
            a3 += bflo(wv.w) * hv.x; a3 += bfhi(wv.w) * hv.y;
        }

        float i_ = sigm(a0);
        float f_ = sigm(a1);
        float g_ = tanh_(a2);
        float o_ = sigm(a3);
        c = f_ * c + i_ * g_;
        float hn = o_ * tanh_(c);
        h = hn;
        __builtin_nontemporal_store(hn, hop);
        hop += H_;

        __syncthreads();   // all hf reads of this step done
        hf[j] = hn;
        __syncthreads();   // new h visible
    }

    state[b * H_ + j] = h;
    state[B_ * H_ + b * H_ + j] = c;
    if (hc_last) {
        hc_last[b * H_ + j] = h;
        hc_last[B_ * H_ + b * H_ + j] = c;
    }
}

extern "C" void kernel_launch(void* const* d_in, const int* in_sizes, int n_in,
                              void* d_out, int out_size, void* d_ws, size_t ws_size,
                              hipStream_t stream)
{
    (void)in_sizes; (void)n_in; (void)out_size;

    const float* x    = (const float*)d_in[0];
    const float* Wih0 = (const float*)d_in[1];
    const float* Whh0 = (const float*)d_in[2];
    const float* b0   = (const float*)d_in[3];
    const float* Wih1 = (const float*)d_in[4];
    const float* Whh1 = (const float*)d_in[5];
    const float* b1   = (const float*)d_in[6];

    float* out   = (float*)d_out;
    float* hlast = out + (size_t)B_ * T_ * H_;

    // ws layout: Wp0 (128 blk), Wp1 (128 blk), state (h+c fp32), xg chunk
    char* ws = (char*)d_ws;
    const size_t WP_BYTES = (size_t)128 * 256 * 16;                 // 524288
    const size_t XG_OFF   = 2 * WP_BYTES + (size_t)2 * B_ * H_ * 4; // 1179648
    uint4* Wp0   = (uint4*)(ws);
    uint4* Wp1   = (uint4*)(ws + WP_BYTES);
    float* state = (float*)(ws + 2 * WP_BYTES);
    void*  xgbuf = (void*)(ws + XG_OFF);

    // Pick xg precision + chunk length that strictly fit ws_size.
    int Tc = -1, XB = 0;
    for (int tc = 2048; tc >= 16; tc >>= 1)
        if (XG_OFF + (size_t)B_ * tc * G_ * 4 <= ws_size) { Tc = tc; XB = 0; break; }
    if (Tc < 0)
        for (int tc = 2048; tc >= 16; tc >>= 1)
            if (XG_OFF + (size_t)B_ * tc * G_ * 2 <= ws_size) { Tc = tc; XB = 1; break; }
    if (Tc < 0) { Tc = 16; XB = 1; }
    int tclog2 = 31 - __builtin_clz((unsigned)Tc);
    int nch = T_ / Tc;

    pack_whh<<<dim3(128, 2), 256, 0, stream>>>(Whh0, Whh1, Wp0, Wp1);

    for (int L = 0; L < 2; ++L) {
        const float* Asrc = L ? (const float*)d_out : x;
        const float* Wih  = L ? Wih1 : Wih0;
        const uint4* Wp   = L ? Wp1 : Wp0;
        const float* bias = L ? b1 : b0;
        for (int ci = 0; ci < nch; ++ci) {
            int t0 = ci * Tc;
            float* hc = (L == 1 && ci == nch - 1) ? hlast : (float*)nullptr;
            if (XB == 0) {
                gemm_xg<0><<<dim3((B_ * Tc) / 64, G_ / 128), 256, 0, stream>>>(
                    Asrc, Wih, xgbuf, tclog2, t0);
                lstm_scan<0><<<B_, 256, 0, stream>>>(
                    xgbuf, Wp, bias, state, out, hc, Tc, t0);
            } else {
                gemm_xg<1><<<dim3((B_ * Tc) / 64, G_ / 128), 256, 0, stream>>>(
                    Asrc, Wih, xgbuf, tclog2, t0);
                lstm_scan<1><<<B_, 256, 0, stream>>>(
                    xgbuf, Wp, bias, state, out, hc, Tc, t0);
            }
        }
    }
}

// Round 6
// 7774.471 us; speedup vs baseline: 38.0001x; 10.9014x over previous
//
#include <hip/hip_runtime.h>
#include <hip/hip_bf16.h>

// 2-layer LSTM, B=64 T=2048 D=H=256, fp32 I/O.
// v6: scan with 2 waves/SIMD + f16 dot2.
//   Round-5 evidence: v5 (full residency, 508 regs) = 1 wave/SIMD, VALUBusy
//   18% on active CUs -> LDS/AGPR latency fully exposed (10-25us/step vs
//   1.8us issue floor). Fix: 512 thr/WG k-split (thread owns 64 k2-blocks:
//   46 in VGPR + 18 in LDS), __launch_bounds__(512,2) -> 2 waves/SIMD with
//   spare regs; W_hh + h in f16, v_dot2_f32_f16 (1 inst per 2 MACs, 4x fewer
//   VALU). xg GEMM moves to f16 MFMA (better precision than bf16).

typedef unsigned short u16;
typedef unsigned int   u32;

typedef __attribute__((ext_vector_type(8))) _Float16 half8;
typedef __attribute__((ext_vector_type(2))) _Float16 half2_t;
typedef __attribute__((ext_vector_type(8))) float    float8;
typedef __attribute__((ext_vector_type(4))) float    f32x4;

#define B_  64
#define T_  2048
#define D_  256
#define H_  256
#define G_  1024   // 4*H

#define NRG 46     // k2-blocks per thread in VGPRs
#define NLD 18     // k2-blocks per thread in LDS (NRG+NLD = 64)
static_assert(NRG + NLD == 64, "k-split coverage");

// ---- helpers ----
__device__ __forceinline__ u16 f2h(float f) {           // RNE fp32->fp16
    union { _Float16 h; u16 b; } v; v.h = (_Float16)f; return v.b;
}
__device__ __forceinline__ float dot2(u32 w, u32 hv, float acc) {
#if __has_builtin(__builtin_amdgcn_fdot2)
    union { u32 u; half2_t h; } a, b;
    a.u = w; b.u = hv;
    return __builtin_amdgcn_fdot2(a.h, b.h, acc, false);
#else
    union { u32 u; _Float16 h[2]; } a, b;
    a.u = w; b.u = hv;
    acc += (float)a.h[0] * (float)b.h[0];
    acc += (float)a.h[1] * (float)b.h[1];
    return acc;
#endif
}
__device__ __forceinline__ float sigm(float x) {
    return 1.0f / (1.0f + __expf(-x));
}
__device__ __forceinline__ float tanh_(float x) {
    float e = __expf(-2.0f * fabsf(x));
    float r = (1.0f - e) / (1.0f + e);
    return x < 0.0f ? -r : r;
}

// ---- pack W_hh [1024][256] fp32 -> Wp[k2][j] = uint4{i,f,g,o} f16-pairs --
// Wp[k2*256+j].x = pack(f16(W[0*256+j][2k2]), f16(W[0*256+j][2k2+1])) etc.
__global__ __launch_bounds__(256) void pack_whh(
    const float* __restrict__ W0, const float* __restrict__ W1,
    uint4* __restrict__ P0, uint4* __restrict__ P1)
{
    const int k2 = blockIdx.x;          // 0..127
    const int j  = threadIdx.x;         // 0..255
    const float* W = blockIdx.y ? W1 : W0;
    uint4*       P = blockIdx.y ? P1 : P0;
    uint4 v;
    u32* vp = &v.x;
#pragma unroll
    for (int g = 0; g < 4; ++g) {
        float2 w = *(const float2*)(W + (size_t)(g * 256 + j) * 256 + 2 * k2);
        vp[g] = (u32)f2h(w.x) | ((u32)f2h(w.y) << 16);
    }
    P[(size_t)k2 * 256 + j] = v;
}

// ---- xg GEMM: out[m][n] = sum_k A[trow(m)][k] * Bw[n][k], f16 MFMA ----
template<int XBF>
__global__ __launch_bounds__(256) void gemm_xg(
    const float* __restrict__ A, const float* __restrict__ Bw,
    void* __restrict__ outv, int tclog2, int t0)
{
    const int tid = threadIdx.x;
    const int l  = tid & 63;
    const int w  = tid >> 6;
    const int m0 = blockIdx.x * 64;
    const int n0 = blockIdx.y * 128 + w * 32;
    const int rl = l & 15;
    const int kl = (l >> 4) * 8;
    const int tcmask = (1 << tclog2) - 1;

    const float* Ab[4];
#pragma unroll
    for (int mi = 0; mi < 4; ++mi) {
        int mbase = m0 + mi * 16;
        int b   = mbase >> tclog2;
        int tcb = mbase & tcmask;
        Ab[mi] = A + ((size_t)b * T_ + t0 + tcb) * D_;
    }

    f32x4 zz = {0.f, 0.f, 0.f, 0.f};
    f32x4 acc[4][2];
#pragma unroll
    for (int mi = 0; mi < 4; ++mi)
#pragma unroll
        for (int ni = 0; ni < 2; ++ni) acc[mi][ni] = zz;

#pragma unroll
    for (int ks = 0; ks < 8; ++ks) {
        const int k = ks * 32 + kl;
        half8 a[4], bb[2];
#pragma unroll
        for (int mi = 0; mi < 4; ++mi) {
            float8 af = *reinterpret_cast<const float8*>(Ab[mi] + (size_t)rl * D_ + k);
#pragma unroll
            for (int r = 0; r < 8; ++r) a[mi][r] = (_Float16)af[r];
        }
#pragma unroll
        for (int ni = 0; ni < 2; ++ni) {
            float8 bf8 = *reinterpret_cast<const float8*>(
                Bw + (size_t)(n0 + ni * 16 + rl) * D_ + k);
#pragma unroll
            for (int r = 0; r < 8; ++r) bb[ni][r] = (_Float16)bf8[r];
        }
#pragma unroll
        for (int mi = 0; mi < 4; ++mi)
#pragma unroll
            for (int ni = 0; ni < 2; ++ni)
                acc[mi][ni] = __builtin_amdgcn_mfma_f32_16x16x32_f16(
                    a[mi], bb[ni], acc[mi][ni], 0, 0, 0);
    }

    // C/D layout: col = lane&15, row = (lane>>4)*4 + reg
    const int rr0 = (l >> 4) * 4;
    const int cc  = l & 15;
#pragma unroll
    for (int mi = 0; mi < 4; ++mi)
#pragma unroll
        for (int ni = 0; ni < 2; ++ni) {
            f32x4 d = acc[mi][ni];
            size_t mrow = (size_t)(m0 + mi * 16 + rr0);
            int col = n0 + ni * 16 + cc;
#pragma unroll
            for (int r = 0; r < 4; ++r) {
                size_t idx = (mrow + r) * G_ + col;
                if (XBF) ((u16*)outv)[idx] = f2h(d[r]);
                else     ((float*)outv)[idx] = d[r];
            }
        }
}

// ---- sequential scan v6: one WG (512 thr) per batch element ----
// thread (j, kh): hidden unit j, k2-half kh (64 k2-blocks: 46 VGPR + 18 LDS).
// h broadcast as packed f16 pairs in LDS; dot via v_dot2_f32_f16; partial
// gate sums exchanged via one float4 LDS write/read.
template<int XBF>
__global__ __launch_bounds__(512, 2) void lstm_scan(
    const void* __restrict__ xgv,        // [B][Tc][1024] fp32 or f16
    const uint4* __restrict__ Wp,        // [128][256] packed f16 pairs
    const float* __restrict__ bias,      // [1024] fp32
    float* __restrict__ state,           // h[64][256], c[64][256] fp32
    float* __restrict__ h_out,           // [B][T_][H_] fp32
    float* __restrict__ hc_last,         // null unless final chunk of layer 2
    int Tc, int t0)
{
    const int b   = blockIdx.x;
    const int tid = threadIdx.x;
    const int j   = tid & 255;
    const int kh  = tid >> 8;

    __shared__ __align__(16) uint4  wl[NLD][512];   // 147456 B
    __shared__ __align__(16) u32    hf_p[128];      //    512 B (f16 pairs)
    __shared__ __align__(16) float4 red[256];       //   4096 B

    // ---- one-time weight residency (per thread: k2 = kh*64 + p) ----
    const uint4* wpb = Wp + (size_t)(kh * 64) * 256 + j;
    uint4 wr[NRG];
#pragma unroll
    for (int p = 0; p < NRG; ++p)
        wr[p] = wpb[(size_t)p * 256];
#pragma unroll
    for (int p = 0; p < NLD; ++p)
        wl[p][tid] = wpb[(size_t)(NRG + p) * 256];

    float h = 0.f, c = 0.f;
    float bi = 0.f, bf_ = 0.f, bg = 0.f, bo = 0.f;
    const float*    xgf = (const float*)xgv;
    const _Float16* xgh = (const _Float16*)xgv;
    size_t xo = (size_t)b * Tc * G_ + j;
    float nx0 = 0.f, nx1 = 0.f, nx2 = 0.f, nx3 = 0.f;
    _Float16* hfh = (_Float16*)hf_p;

    if (kh == 0) {
        if (t0) {
            h = state[b * H_ + j];
            c = state[B_ * H_ + b * H_ + j];
        }
        bi  = bias[j];
        bf_ = bias[256 + j];
        bg  = bias[512 + j];
        bo  = bias[768 + j];
        hfh[j] = (_Float16)h;
        if (XBF) {
            nx0 = (float)xgh[xo];       nx1 = (float)xgh[xo + 256];
            nx2 = (float)xgh[xo + 512]; nx3 = (float)xgh[xo + 768];
        } else {
            nx0 = __builtin_nontemporal_load(xgf + xo);
            nx1 = __builtin_nontemporal_load(xgf + xo + 256);
            nx2 = __builtin_nontemporal_load(xgf + xo + 512);
            nx3 = __builtin_nontemporal_load(xgf + xo + 768);
        }
    }
    const uint4* hv4p = ((const uint4*)hf_p) + kh * 16;  // 16 uint4 = 64 k2
    float* hop = h_out + ((size_t)b * T_ + t0) * H_ + j;
    __syncthreads();

    for (int t = 0; t < Tc; ++t) {
        float a0, a1, a2, a3;
        if (kh == 0) {
            a0 = nx0 + bi; a1 = nx1 + bf_; a2 = nx2 + bg; a3 = nx3 + bo;
            if (t + 1 < Tc) xo += G_;            // clamped prefetch
            if (XBF) {
                nx0 = (float)xgh[xo];       nx1 = (float)xgh[xo + 256];
                nx2 = (float)xgh[xo + 512]; nx3 = (float)xgh[xo + 768];
            } else {
                nx0 = __builtin_nontemporal_load(xgf + xo);
                nx1 = __builtin_nontemporal_load(xgf + xo + 256);
                nx2 = __builtin_nontemporal_load(xgf + xo + 512);
                nx3 = __builtin_nontemporal_load(xgf + xo + 768);
            }
        } else {
            a0 = a1 = a2 = a3 = 0.f;
        }

        // dot over this thread's 64 k2-blocks (4 per hv uint4)
#pragma unroll
        for (int i = 0; i < 16; ++i) {
            uint4 hv4 = hv4p[i];                 // broadcast read
            const u32* hq = &hv4.x;
#pragma unroll
            for (int q = 0; q < 4; ++q) {
                const int p = 4 * i + q;         // compile-time
                uint4 wv;
                if (p < NRG) wv = wr[p];
                else         wv = wl[p - NRG][tid];
                u32 hv = hq[q];
                a0 = dot2(wv.x, hv, a0);
                a1 = dot2(wv.y, hv, a1);
                a2 = dot2(wv.z, hv, a2);
                a3 = dot2(wv.w, hv, a3);
            }
        }

        if (kh == 1) {
            float4 r4; r4.x = a0; r4.y = a1; r4.z = a2; r4.w = a3;
            red[j] = r4;
        }
        __syncthreads();   // partials visible; all hv reads of step done
        if (kh == 0) {
            float4 r4 = red[j];
            a0 += r4.x; a1 += r4.y; a2 += r4.z; a3 += r4.w;
            float i_ = sigm(a0);
            float f_ = sigm(a1);
            float g_ = tanh_(a2);
            float o_ = sigm(a3);
            c = f_ * c + i_ * g_;
            float hn = o_ * tanh_(c);
            h = hn;
            hfh[j] = (_Float16)hn;
            __builtin_nontemporal_store(hn, hop);
            hop += H_;
        }
        __syncthreads();   // new h visible
    }

    if (kh == 0) {
        state[b * H_ + j] = h;
        state[B_ * H_ + b * H_ + j] = c;
        if (hc_last) {
            hc_last[b * H_ + j] = h;
            hc_last[B_ * H_ + b * H_ + j] = c;
        }
    }
}

extern "C" void kernel_launch(void* const* d_in, const int* in_sizes, int n_in,
                              void* d_out, int out_size, void* d_ws, size_t ws_size,
                              hipStream_t stream)
{
    (void)in_sizes; (void)n_in; (void)out_size;

    const float* x    = (const float*)d_in[0];
    const float* Wih0 = (const float*)d_in[1];
    const float* Whh0 = (const float*)d_in[2];
    const float* b0   = (const float*)d_in[3];
    const float* Wih1 = (const float*)d_in[4];
    const float* Whh1 = (const float*)d_in[5];
    const float* b1   = (const float*)d_in[6];

    float* out   = (float*)d_out;
    float* hlast = out + (size_t)B_ * T_ * H_;

    // ws layout: Wp0 (128 blk), Wp1 (128 blk), state (h+c fp32), xg chunk
    char* ws = (char*)d_ws;
    const size_t WP_BYTES = (size_t)128 * 256 * 16;                 // 524288
    const size_t XG_OFF   = 2 * WP_BYTES + (size_t)2 * B_ * H_ * 4; // 1179648
    uint4* Wp0   = (uint4*)(ws);
    uint4* Wp1   = (uint4*)(ws + WP_BYTES);
    float* state = (float*)(ws + 2 * WP_BYTES);
    void*  xgbuf = (void*)(ws + XG_OFF);

    // Pick xg precision + chunk length that strictly fit ws_size.
    int Tc = -1, XB = 0;
    for (int tc = 2048; tc >= 16; tc >>= 1)
        if (XG_OFF + (size_t)B_ * tc * G_ * 4 <= ws_size) { Tc = tc; XB = 0; break; }
    if (Tc < 0)
        for (int tc = 2048; tc >= 16; tc >>= 1)
            if (XG_OFF + (size_t)B_ * tc * G_ * 2 <= ws_size) { Tc = tc; XB = 1; break; }
    if (Tc < 0) { Tc = 16; XB = 1; }
    int tclog2 = 31 - __builtin_clz((unsigned)Tc);
    int nch = T_ / Tc;

    pack_whh<<<dim3(128, 2), 256, 0, stream>>>(Whh0, Whh1, Wp0, Wp1);

    for (int L = 0; L < 2; ++L) {
        const float* Asrc = L ? (const float*)d_out : x;
        const float* Wih  = L ? Wih1 : Wih0;
        const uint4* Wp   = L ? Wp1 : Wp0;
        const float* bias = L ? b1 : b0;
        for (int ci = 0; ci < nch; ++ci) {
            int t0 = ci * Tc;
            float* hc = (L == 1 && ci == nch - 1) ? hlast : (float*)nullptr;
            if (XB == 0) {
                gemm_xg<0><<<dim3((B_ * Tc) / 64, G_ / 128), 256, 0, stream>>>(
                    Asrc, Wih, xgbuf, tclog2, t0);
                lstm_scan<0><<<B_, 512, 0, stream>>>(
                    xgbuf, Wp, bias, state, out, hc, Tc, t0);
            } else {
                gemm_xg<1><<<dim3((B_ * Tc) / 64, G_ / 128), 256, 0, stream>>>(
                    Asrc, Wih, xgbuf, tclog2, t0);
                lstm_scan<1><<<B_, 512, 0, stream>>>(
                    xgbuf, Wp, bias, state, out, hc, Tc, t0);
            }
        }
    }
}

// Round 7
// 6688.911 us; speedup vs baseline: 44.1672x; 1.1623x over previous
//
#include <hip/hip_runtime.h>
#include <hip/hip_bf16.h>

// 2-layer LSTM, B=64 T=2048 D=H=256, fp32 I/O.
// v7: gemm rebuilt (round-6 evidence: gemm = 2.2ms each = 58% of runtime,
//     8x A re-fetch + per-use cvt + fp32 xg traffic).
//   - gemm: 1 WG per 64-row M-tile, full N loop; A staged once in LDS f16;
//     W_ih pre-packed f16; xg written f16 (halves write + scan read).
//   - h1 stored f16 in ws (layer-2 gemm quantizes to f16 anyway -> free).
//   - scan: unchanged v6 structure (512 thr, 2 waves/SIMD, dot2, weights
//     resident VGPR+LDS) -- measured 66% VALUBusy on active CUs, near limit.

typedef unsigned short u16;
typedef unsigned int   u32;

typedef __attribute__((ext_vector_type(8))) _Float16       half8;
typedef __attribute__((ext_vector_type(2))) _Float16       half2_t;
typedef __attribute__((ext_vector_type(8))) unsigned short ushort8;
typedef __attribute__((ext_vector_type(4))) float          f32x4;

#define B_  64
#define T_  2048
#define D_  256
#define H_  256
#define G_  1024   // 4*H

#define NRG 46     // scan: k2-blocks per thread in VGPRs
#define NLD 18     // scan: k2-blocks per thread in LDS (NRG+NLD = 64)
static_assert(NRG + NLD == 64, "k-split coverage");

// ---- helpers ----
__device__ __forceinline__ u16 f2h(float f) {           // RNE fp32->fp16
    union { _Float16 h; u16 b; } v; v.h = (_Float16)f; return v.b;
}
__device__ __forceinline__ float dot2(u32 w, u32 hv, float acc) {
#if __has_builtin(__builtin_amdgcn_fdot2)
    union { u32 u; half2_t h; } a, b;
    a.u = w; b.u = hv;
    return __builtin_amdgcn_fdot2(a.h, b.h, acc, false);
#else
    union { u32 u; _Float16 h[2]; } a, b;
    a.u = w; b.u = hv;
    acc += (float)a.h[0] * (float)b.h[0];
    acc += (float)a.h[1] * (float)b.h[1];
    return acc;
#endif
}
__device__ __forceinline__ float sigm(float x) {
    return 1.0f / (1.0f + __expf(-x));
}
__device__ __forceinline__ float tanh_(float x) {
    float e = __expf(-2.0f * fabsf(x));
    float r = (1.0f - e) / (1.0f + e);
    return x < 0.0f ? -r : r;
}

// ---- pack W_hh [1024][256] fp32 -> Wp[k2][j] = uint4{i,f,g,o} f16-pairs --
__global__ __launch_bounds__(256) void pack_whh(
    const float* __restrict__ W0, const float* __restrict__ W1,
    uint4* __restrict__ P0, uint4* __restrict__ P1)
{
    const int k2 = blockIdx.x;          // 0..127
    const int j  = threadIdx.x;         // 0..255
    const float* W = blockIdx.y ? W1 : W0;
    uint4*       P = blockIdx.y ? P1 : P0;
    uint4 v;
    u32* vp = &v.x;
#pragma unroll
    for (int g = 0; g < 4; ++g) {
        float2 w = *(const float2*)(W + (size_t)(g * 256 + j) * 256 + 2 * k2);
        vp[g] = (u32)f2h(w.x) | ((u32)f2h(w.y) << 16);
    }
    P[(size_t)k2 * 256 + j] = v;
}

// ---- pack W_ih [1024][256] fp32 -> f16 row-major (both layers) ----
__global__ __launch_bounds__(256) void pack_wih(
    const float* __restrict__ W0, const float* __restrict__ W1,
    u16* __restrict__ O0, u16* __restrict__ O1)
{
    const float* W = blockIdx.y ? W1 : W0;
    u16*         O = blockIdx.y ? O1 : O0;
    size_t i = (size_t)blockIdx.x * 256 + threadIdx.x;   // over 65536 float4
    float4 v = ((const float4*)W)[i];
    u32 lo = (u32)f2h(v.x) | ((u32)f2h(v.y) << 16);
    u32 hi = (u32)f2h(v.z) | ((u32)f2h(v.w) << 16);
    uint2 u; u.x = lo; u.y = hi;
    ((uint2*)O)[i] = u;
}

// ---- xg GEMM v2: out[m][n] = sum_k A[grow(m)][k] * Bh[n][k], f16 MFMA ----
// One WG per 64-row M-tile; A staged once in LDS f16 [64][264]; full N=1024
// loop (8 blocks of 128, wave w owns cols w*32..w*32+31 of each block).
// out is f16 [B*Tc][1024]. Per-row global mapping: m = b*Tc+tc.
template<int AHALF>
__global__ __launch_bounds__(256) void gemm_xg(
    const void* __restrict__ Av, const u16* __restrict__ Bh,
    u16* __restrict__ out, int tclog2, int t0)
{
    __shared__ __align__(16) u16 As[64][264];   // 33792 B, pad 8 f16
    const int tid    = threadIdx.x;
    const int m0     = blockIdx.x * 64;
    const int tcmask = (1 << tclog2) - 1;

    // ---- stage A tile (64 rows x 256 k) into LDS as f16 ----
    if (AHALF) {
        const u16* Ah = (const u16*)Av;
#pragma unroll
        for (int it = 0; it < 8; ++it) {
            int idx = it * 256 + tid;            // 2048 = 64 rows x 32 u16x8
            int row = idx >> 5;
            int c8  = idx & 31;
            int m   = m0 + row;
            size_t grow = (size_t)(m >> tclog2) * T_ + t0 + (m & tcmask);
            ushort8 v = *(const ushort8*)(Ah + grow * D_ + c8 * 8);
            *(ushort8*)(&As[row][c8 * 8]) = v;
        }
    } else {
        const float* Af = (const float*)Av;
#pragma unroll
        for (int it = 0; it < 16; ++it) {
            int idx = it * 256 + tid;            // 4096 = 64 rows x 64 f32x4
            int row = idx >> 6;
            int c4  = idx & 63;
            int m   = m0 + row;
            size_t grow = (size_t)(m >> tclog2) * T_ + t0 + (m & tcmask);
            float4 v = *(const float4*)(Af + grow * D_ + c4 * 4);
            uint2 u;
            u.x = (u32)f2h(v.x) | ((u32)f2h(v.y) << 16);
            u.y = (u32)f2h(v.z) | ((u32)f2h(v.w) << 16);
            *(uint2*)(&As[row][c4 * 4]) = u;
        }
    }
    __syncthreads();

    const int l   = tid & 63;
    const int w   = tid >> 6;
    const int rl  = l & 15;
    const int kg  = l >> 4;          // k-offset group (x8)
    const int rr0 = kg * 4;          // C/D row base

    for (int nb = 0; nb < 8; ++nb) {
        const int n0 = nb * 128 + w * 32;
        f32x4 zz = {0.f, 0.f, 0.f, 0.f};
        f32x4 acc[4][2];
#pragma unroll
        for (int mi = 0; mi < 4; ++mi)
#pragma unroll
            for (int ni = 0; ni < 2; ++ni) acc[mi][ni] = zz;

#pragma unroll
        for (int ks = 0; ks < 8; ++ks) {
            const int k = ks * 32 + kg * 8;
            half8 a[4], bb[2];
#pragma unroll
            for (int mi = 0; mi < 4; ++mi)
                a[mi] = *(const half8*)(&As[mi * 16 + rl][k]);
#pragma unroll
            for (int ni = 0; ni < 2; ++ni)
                bb[ni] = *(const half8*)(Bh + (size_t)(n0 + ni * 16 + rl) * D_ + k);
#pragma unroll
            for (int mi = 0; mi < 4; ++mi)
#pragma unroll
                for (int ni = 0; ni < 2; ++ni)
                    acc[mi][ni] = __builtin_amdgcn_mfma_f32_16x16x32_f16(
                        a[mi], bb[ni], acc[mi][ni], 0, 0, 0);
        }

        // C/D layout: col = lane&15, row = (lane>>4)*4 + reg
#pragma unroll
        for (int mi = 0; mi < 4; ++mi)
#pragma unroll
            for (int ni = 0; ni < 2; ++ni) {
                f32x4 d = acc[mi][ni];
                size_t mrow = (size_t)(m0 + mi * 16 + rr0);
                int col = n0 + ni * 16 + rl;
#pragma unroll
                for (int r = 0; r < 4; ++r)
                    out[(mrow + r) * G_ + col] = f2h(d[r]);
            }
    }
}

// ---- sequential scan: one WG (512 thr) per batch element (v6 structure) --
// thread (j, kh): hidden unit j, k2-half kh (64 k2-blocks: 46 VGPR + 18 LDS).
// xg is f16. HOUTH: 1 -> h_out is u16 f16 (layer-1 h1 buffer); 0 -> fp32.
template<int HOUTH>
__global__ __launch_bounds__(512, 2) void lstm_scan(
    const _Float16* __restrict__ xg,     // [B][Tc][1024] f16
    const uint4* __restrict__ Wp,        // [128][256] packed f16 pairs
    const float* __restrict__ bias,      // [1024] fp32
    float* __restrict__ state,           // h[64][256], c[64][256] fp32
    void* __restrict__ h_out,            // [B][T_][H_] f16 or fp32
    float* __restrict__ hc_last,         // null unless final chunk of layer 2
    int Tc, int t0)
{
    const int b   = blockIdx.x;
    const int tid = threadIdx.x;
    const int j   = tid & 255;
    const int kh  = tid >> 8;

    __shared__ __align__(16) uint4  wl[NLD][512];   // 147456 B
    __shared__ __align__(16) u32    hf_p[128];      //    512 B (f16 pairs)
    __shared__ __align__(16) float4 red[256];       //   4096 B

    // ---- one-time weight residency (per thread: k2 = kh*64 + p) ----
    const uint4* wpb = Wp + (size_t)(kh * 64) * 256 + j;
    uint4 wr[NRG];
#pragma unroll
    for (int p = 0; p < NRG; ++p)
        wr[p] = wpb[(size_t)p * 256];
#pragma unroll
    for (int p = 0; p < NLD; ++p)
        wl[p][tid] = wpb[(size_t)(NRG + p) * 256];

    float h = 0.f, c = 0.f;
    float bi = 0.f, bf_ = 0.f, bg = 0.f, bo = 0.f;
    size_t xo = (size_t)b * Tc * G_ + j;
    float nx0 = 0.f, nx1 = 0.f, nx2 = 0.f, nx3 = 0.f;
    _Float16* hfh = (_Float16*)hf_p;

    if (kh == 0) {
        if (t0) {
            h = state[b * H_ + j];
            c = state[B_ * H_ + b * H_ + j];
        }
        bi  = bias[j];
        bf_ = bias[256 + j];
        bg  = bias[512 + j];
        bo  = bias[768 + j];
        hfh[j] = (_Float16)h;
        nx0 = (float)xg[xo];       nx1 = (float)xg[xo + 256];
        nx2 = (float)xg[xo + 512]; nx3 = (float)xg[xo + 768];
    }
    const uint4* hv4p = ((const uint4*)hf_p) + kh * 16;  // 16 uint4 = 64 k2
    float* hof = (float*)h_out;
    u16*   hoh = (u16*)h_out;
    size_t ho = ((size_t)b * T_ + t0) * H_ + j;
    __syncthreads();

    for (int t = 0; t < Tc; ++t) {
        float a0, a1, a2, a3;
        if (kh == 0) {
            a0 = nx0 + bi; a1 = nx1 + bf_; a2 = nx2 + bg; a3 = nx3 + bo;
            if (t + 1 < Tc) xo += G_;            // clamped prefetch
            nx0 = (float)xg[xo];       nx1 = (float)xg[xo + 256];
            nx2 = (float)xg[xo + 512]; nx3 = (float)xg[xo + 768];
        } else {
            a0 = a1 = a2 = a3 = 0.f;
        }

        // dot over this thread's 64 k2-blocks (4 per hv uint4)
#pragma unroll
        for (int i = 0; i < 16; ++i) {
            uint4 hv4 = hv4p[i];                 // broadcast read
            const u32* hq = &hv4.x;
#pragma unroll
            for (int q = 0; q < 4; ++q) {
                const int p = 4 * i + q;         // compile-time
                uint4 wv;
                if (p < NRG) wv = wr[p];
                else         wv = wl[p - NRG][tid];
                u32 hv = hq[q];
                a0 = dot2(wv.x, hv, a0);
                a1 = dot2(wv.y, hv, a1);
                a2 = dot2(wv.z, hv, a2);
                a3 = dot2(wv.w, hv, a3);
            }
        }

        if (kh == 1) {
            float4 r4; r4.x = a0; r4.y = a1; r4.z = a2; r4.w = a3;
            red[j] = r4;
        }
        __syncthreads();   // partials visible; all hv reads of step done
        if (kh == 0) {
            float4 r4 = red[j];
            a0 += r4.x; a1 += r4.y; a2 += r4.z; a3 += r4.w;
            float i_ = sigm(a0);
            float f_ = sigm(a1);
            float g_ = tanh_(a2);
            float o_ = sigm(a3);
            c = f_ * c + i_ * g_;
            float hn = o_ * tanh_(c);
            h = hn;
            hfh[j] = (_Float16)hn;
            if (HOUTH) hoh[ho] = f2h(hn);
            else       __builtin_nontemporal_store(hn, hof + ho);
            ho += H_;
        }
        __syncthreads();   // new h visible
    }

    if (kh == 0) {
        state[b * H_ + j] = h;
        state[B_ * H_ + b * H_ + j] = c;
        if (hc_last) {
            hc_last[b * H_ + j] = h;
            hc_last[B_ * H_ + b * H_ + j] = c;
        }
    }
}

extern "C" void kernel_launch(void* const* d_in, const int* in_sizes, int n_in,
                              void* d_out, int out_size, void* d_ws, size_t ws_size,
                              hipStream_t stream)
{
    (void)in_sizes; (void)n_in; (void)out_size;

    const float* x    = (const float*)d_in[0];
    const float* Wih0 = (const float*)d_in[1];
    const float* Whh0 = (const float*)d_in[2];
    const float* b0   = (const float*)d_in[3];
    const float* Wih1 = (const float*)d_in[4];
    const float* Whh1 = (const float*)d_in[5];
    const float* b1   = (const float*)d_in[6];

    float* out   = (float*)d_out;
    float* hlast = out + (size_t)B_ * T_ * H_;

    // ws layout
    char* ws = (char*)d_ws;
    const size_t WPB  = (size_t)128 * 256 * 16;     // 524288 per packed W_hh
    const size_t WIHB = (size_t)1024 * 256 * 2;     // 524288 per f16 W_ih
    const size_t STB  = (size_t)2 * B_ * H_ * 4;    // 131072 state
    uint4* Wp0   = (uint4*)(ws);
    uint4* Wp1   = (uint4*)(ws + WPB);
    u16*   Wih0h = (u16*)(ws + 2 * WPB);
    u16*   Wih1h = (u16*)(ws + 2 * WPB + WIHB);
    float* state = (float*)(ws + 2 * WPB + 2 * WIHB);
    const size_t BASE = 2 * WPB + 2 * WIHB + STB;   // 2228224
    const size_t H1SZ = (size_t)B_ * T_ * H_ * 2;   // 64 MiB h1 f16

    // Pick layout: prefer h1-as-f16 + largest xg chunk; fall back as needed.
    int Tc = -1, H1F = 0;
    for (int tc = 2048; tc >= 16; tc >>= 1)
        if (BASE + H1SZ + (size_t)B_ * tc * G_ * 2 <= ws_size) { Tc = tc; H1F = 1; break; }
    if (Tc < 0)
        for (int tc = 2048; tc >= 16; tc >>= 1)
            if (BASE + (size_t)B_ * tc * G_ * 2 <= ws_size) { Tc = tc; H1F = 0; break; }
    if (Tc < 0) { Tc = 16; H1F = 0; }
    u16*      h1h   = (u16*)(ws + BASE);
    _Float16* xgbuf = (_Float16*)(ws + BASE + (H1F ? H1SZ : 0));
    int tclog2 = 31 - __builtin_clz((unsigned)Tc);
    int nch = T_ / Tc;

    pack_whh<<<dim3(128, 2), 256, 0, stream>>>(Whh0, Whh1, Wp0, Wp1);
    pack_wih<<<dim3(256, 2), 256, 0, stream>>>(Wih0, Wih1, Wih0h, Wih1h);

    for (int ci = 0; ci < nch; ++ci) {          // layer 0
        int t0 = ci * Tc;
        gemm_xg<0><<<dim3((B_ * Tc) / 64), 256, 0, stream>>>(
            x, Wih0h, (u16*)xgbuf, tclog2, t0);
        if (H1F)
            lstm_scan<1><<<B_, 512, 0, stream>>>(
                xgbuf, Wp0, b0, state, h1h, (float*)nullptr, Tc, t0);
        else
            lstm_scan<0><<<B_, 512, 0, stream>>>(
                xgbuf, Wp0, b0, state, out, (float*)nullptr, Tc, t0);
    }
    for (int ci = 0; ci < nch; ++ci) {          // layer 1
        int t0 = ci * Tc;
        float* hc = (ci == nch - 1) ? hlast : (float*)nullptr;
        if (H1F)
            gemm_xg<1><<<dim3((B_ * Tc) / 64), 256, 0, stream>>>(
                h1h, Wih1h, (u16*)xgbuf, tclog2, t0);
        else
            gemm_xg<0><<<dim3((B_ * Tc) / 64), 256, 0, stream>>>(
                out, Wih1h, (u16*)xgbuf, tclog2, t0);
        lstm_scan<0><<<B_, 512, 0, stream>>>(
            xgbuf, Wp1, b1, state, out, hc, Tc, t0);
    }
}

// Round 8
// 3963.726 us; speedup vs baseline: 74.5335x; 1.6875x over previous
//
#include <hip/hip_runtime.h>
#include <hip/hip_bf16.h>

// 2-layer LSTM, B=64 T=2048 D=H=256, fp32 I/O.
// v8: chunked cross-layer pipelining.
//   Round-7 evidence: scan = 2 x 3.25ms = 97% of runtime, 1.6us/step,
//   only 64/256 CUs active, layers serialized. Per-WG scan is within ~1.7x
//   of its issue+LDS floor and its reg/LDS budget is saturated -> the win is
//   occupancy: run layer-0 chunk s and layer-1 chunk s-1 CONCURRENTLY as one
//   128-WG dual-job dispatch (deps ride in-stream dispatch order only).
//   Scan wall ~ (nch+1)/(2 nch) of serial. Tc=256, nch=8.
//   Inner scan loop identical to verified v7 body (HOUTH now runtime-uniform).

typedef unsigned short u16;
typedef unsigned int   u32;

typedef __attribute__((ext_vector_type(8))) _Float16       half8;
typedef __attribute__((ext_vector_type(2))) _Float16       half2_t;
typedef __attribute__((ext_vector_type(8))) unsigned short ushort8;
typedef __attribute__((ext_vector_type(4))) float          f32x4;

#define B_  64
#define T_  2048
#define D_  256
#define H_  256
#define G_  1024   // 4*H

#define NRG 46     // scan: k2-blocks per thread in VGPRs
#define NLD 18     // scan: k2-blocks per thread in LDS (NRG+NLD = 64)
static_assert(NRG + NLD == 64, "k-split coverage");

// ---- helpers ----
__device__ __forceinline__ u16 f2h(float f) {           // RNE fp32->fp16
    union { _Float16 h; u16 b; } v; v.h = (_Float16)f; return v.b;
}
__device__ __forceinline__ float dot2(u32 w, u32 hv, float acc) {
#if __has_builtin(__builtin_amdgcn_fdot2)
    union { u32 u; half2_t h; } a, b;
    a.u = w; b.u = hv;
    return __builtin_amdgcn_fdot2(a.h, b.h, acc, false);
#else
    union { u32 u; _Float16 h[2]; } a, b;
    a.u = w; b.u = hv;
    acc += (float)a.h[0] * (float)b.h[0];
    acc += (float)a.h[1] * (float)b.h[1];
    return acc;
#endif
}
__device__ __forceinline__ float sigm(float x) {
    return 1.0f / (1.0f + __expf(-x));
}
__device__ __forceinline__ float tanh_(float x) {
    float e = __expf(-2.0f * fabsf(x));
    float r = (1.0f - e) / (1.0f + e);
    return x < 0.0f ? -r : r;
}

// ---- pack W_hh [1024][256] fp32 -> Wp[k2][j] = uint4{i,f,g,o} f16-pairs --
__global__ __launch_bounds__(256) void pack_whh(
    const float* __restrict__ W0, const float* __restrict__ W1,
    uint4* __restrict__ P0, uint4* __restrict__ P1)
{
    const int k2 = blockIdx.x;          // 0..127
    const int j  = threadIdx.x;         // 0..255
    const float* W = blockIdx.y ? W1 : W0;
    uint4*       P = blockIdx.y ? P1 : P0;
    uint4 v;
    u32* vp = &v.x;
#pragma unroll
    for (int g = 0; g < 4; ++g) {
        float2 w = *(const float2*)(W + (size_t)(g * 256 + j) * 256 + 2 * k2);
        vp[g] = (u32)f2h(w.x) | ((u32)f2h(w.y) << 16);
    }
    P[(size_t)k2 * 256 + j] = v;
}

// ---- pack W_ih [1024][256] fp32 -> f16 row-major (both layers) ----
__global__ __launch_bounds__(256) void pack_wih(
    const float* __restrict__ W0, const float* __restrict__ W1,
    u16* __restrict__ O0, u16* __restrict__ O1)
{
    const float* W = blockIdx.y ? W1 : W0;
    u16*         O = blockIdx.y ? O1 : O0;
    size_t i = (size_t)blockIdx.x * 256 + threadIdx.x;   // over 65536 float4
    float4 v = ((const float4*)W)[i];
    u32 lo = (u32)f2h(v.x) | ((u32)f2h(v.y) << 16);
    u32 hi = (u32)f2h(v.z) | ((u32)f2h(v.w) << 16);
    uint2 u; u.x = lo; u.y = hi;
    ((uint2*)O)[i] = u;
}

// ---- xg GEMM: out[m][n] = sum_k A[grow(m)][k] * Bh[n][k], f16 MFMA ----
// One WG per 64-row M-tile; A staged once in LDS f16 [64][264]; full N=1024
// loop. out is f16 [B*Tc][1024] (chunk-row indexed). A-row mapping:
// grow = (m>>tclog2)*Tstride + t0 + (m&tcmask).
template<int AHALF>
__global__ __launch_bounds__(256) void gemm_xg(
    const void* __restrict__ Av, const u16* __restrict__ Bh,
    u16* __restrict__ out, int tclog2, int Tstride, int t0)
{
    __shared__ __align__(16) u16 As[64][264];   // 33792 B
    const int tid    = threadIdx.x;
    const int m0     = blockIdx.x * 64;
    const int tcmask = (1 << tclog2) - 1;

    if (AHALF) {
        const u16* Ah = (const u16*)Av;
#pragma unroll
        for (int it = 0; it < 8; ++it) {
            int idx = it * 256 + tid;            // 2048 = 64 rows x 32 u16x8
            int row = idx >> 5;
            int c8  = idx & 31;
            int m   = m0 + row;
            size_t grow = (size_t)(m >> tclog2) * Tstride + t0 + (m & tcmask);
            ushort8 v = *(const ushort8*)(Ah + grow * D_ + c8 * 8);
            *(ushort8*)(&As[row][c8 * 8]) = v;
        }
    } else {
        const float* Af = (const float*)Av;
#pragma unroll
        for (int it = 0; it < 16; ++it) {
            int idx = it * 256 + tid;            // 4096 = 64 rows x 64 f32x4
            int row = idx >> 6;
            int c4  = idx & 63;
            int m   = m0 + row;
            size_t grow = (size_t)(m >> tclog2) * Tstride + t0 + (m & tcmask);
            float4 v = *(const float4*)(Af + grow * D_ + c4 * 4);
            uint2 u;
            u.x = (u32)f2h(v.x) | ((u32)f2h(v.y) << 16);
            u.y = (u32)f2h(v.z) | ((u32)f2h(v.w) << 16);
            *(uint2*)(&As[row][c4 * 4]) = u;
        }
    }
    __syncthreads();

    const int l   = tid & 63;
    const int w   = tid >> 6;
    const int rl  = l & 15;
    const int kg  = l >> 4;
    const int rr0 = kg * 4;

    for (int nb = 0; nb < 8; ++nb) {
        const int n0 = nb * 128 + w * 32;
        f32x4 zz = {0.f, 0.f, 0.f, 0.f};
        f32x4 acc[4][2];
#pragma unroll
        for (int mi = 0; mi < 4; ++mi)
#pragma unroll
            for (int ni = 0; ni < 2; ++ni) acc[mi][ni] = zz;

#pragma unroll
        for (int ks = 0; ks < 8; ++ks) {
            const int k = ks * 32 + kg * 8;
            half8 a[4], bb[2];
#pragma unroll
            for (int mi = 0; mi < 4; ++mi)
                a[mi] = *(const half8*)(&As[mi * 16 + rl][k]);
#pragma unroll
            for (int ni = 0; ni < 2; ++ni)
                bb[ni] = *(const half8*)(Bh + (size_t)(n0 + ni * 16 + rl) * D_ + k);
#pragma unroll
            for (int mi = 0; mi < 4; ++mi)
#pragma unroll
                for (int ni = 0; ni < 2; ++ni)
                    acc[mi][ni] = __builtin_amdgcn_mfma_f32_16x16x32_f16(
                        a[mi], bb[ni], acc[mi][ni], 0, 0, 0);
        }

        // C/D layout: col = lane&15, row = (lane>>4)*4 + reg
#pragma unroll
        for (int mi = 0; mi < 4; ++mi)
#pragma unroll
            for (int ni = 0; ni < 2; ++ni) {
                f32x4 d = acc[mi][ni];
                size_t mrow = (size_t)(m0 + mi * 16 + rr0);
                int col = n0 + ni * 16 + rl;
#pragma unroll
                for (int r = 0; r < 4; ++r)
                    out[(mrow + r) * G_ + col] = f2h(d[r]);
            }
    }
}

// ---- dual-job sequential scan: 128 WGs = 2 jobs x 64 batch elements ----
// WGs [0,64): job A (layer 0, chunk s); WGs [64,128): job B (layer 1,
// chunk s-1). Jobs are independent; deps ride dispatch order.
// Per-WG body identical to v7: thread (j,kh) owns 64 k2-blocks
// (46 VGPR + 18 LDS), h broadcast as f16 pairs in LDS, dot2, float4 red.
struct ScanJob {
    const _Float16* xg;      // [64][Tc][1024] f16
    const uint4*    Wp;      // [128][256]
    const float*    bias;    // [1024]
    float*          state;   // h[64][256], c[64][256]
    void*           h_out;   // f16 (houth=1) or fp32
    float*          hc_last; // may be null
    int Tc;                  // 0 = inactive
    int toff;                // h_out time offset
    int TS;                  // h_out time stride
    int houth;               // 1 = f16 h_out
    int first;               // 1 = zero-init state
};

__global__ __launch_bounds__(512, 2) void lstm_scan2(ScanJob JA, ScanJob JB)
{
    const ScanJob J = (blockIdx.x >= 64) ? JB : JA;
    if (J.Tc == 0) return;
    const int b   = blockIdx.x & 63;
    const int tid = threadIdx.x;
    const int j   = tid & 255;
    const int kh  = tid >> 8;

    __shared__ __align__(16) uint4  wl[NLD][512];   // 147456 B
    __shared__ __align__(16) u32    hf_p[128];      //    512 B (f16 pairs)
    __shared__ __align__(16) float4 red[256];       //   4096 B

    // ---- one-time weight residency (per thread: k2 = kh*64 + p) ----
    const uint4* wpb = J.Wp + (size_t)(kh * 64) * 256 + j;
    uint4 wr[NRG];
#pragma unroll
    for (int p = 0; p < NRG; ++p)
        wr[p] = wpb[(size_t)p * 256];
#pragma unroll
    for (int p = 0; p < NLD; ++p)
        wl[p][tid] = wpb[(size_t)(NRG + p) * 256];

    const int Tc = J.Tc;
    const int houth = J.houth;
    float h = 0.f, c = 0.f;
    float bi = 0.f, bf_ = 0.f, bg = 0.f, bo = 0.f;
    const _Float16* xg = J.xg;
    size_t xo = (size_t)b * Tc * G_ + j;
    float nx0 = 0.f, nx1 = 0.f, nx2 = 0.f, nx3 = 0.f;
    _Float16* hfh = (_Float16*)hf_p;

    if (kh == 0) {
        if (!J.first) {
            h = J.state[b * H_ + j];
            c = J.state[B_ * H_ + b * H_ + j];
        }
        bi  = J.bias[j];
        bf_ = J.bias[256 + j];
        bg  = J.bias[512 + j];
        bo  = J.bias[768 + j];
        hfh[j] = (_Float16)h;
        nx0 = (float)xg[xo];       nx1 = (float)xg[xo + 256];
        nx2 = (float)xg[xo + 512]; nx3 = (float)xg[xo + 768];
    }
    const uint4* hv4p = ((const uint4*)hf_p) + kh * 16;  // 16 uint4 = 64 k2
    float* hof = (float*)J.h_out;
    u16*   hoh = (u16*)J.h_out;
    size_t ho = ((size_t)b * J.TS + J.toff) * H_ + j;
    __syncthreads();

    for (int t = 0; t < Tc; ++t) {
        float a0, a1, a2, a3;
        if (kh == 0) {
            a0 = nx0 + bi; a1 = nx1 + bf_; a2 = nx2 + bg; a3 = nx3 + bo;
            if (t + 1 < Tc) xo += G_;            // clamped prefetch
            nx0 = (float)xg[xo];       nx1 = (float)xg[xo + 256];
            nx2 = (float)xg[xo + 512]; nx3 = (float)xg[xo + 768];
        } else {
            a0 = a1 = a2 = a3 = 0.f;
        }

        // dot over this thread's 64 k2-blocks (4 per hv uint4)
#pragma unroll
        for (int i = 0; i < 16; ++i) {
            uint4 hv4 = hv4p[i];                 // broadcast read
            const u32* hq = &hv4.x;
#pragma unroll
            for (int q = 0; q < 4; ++q) {
                const int p = 4 * i + q;         // compile-time
                uint4 wv;
                if (p < NRG) wv = wr[p];
                else         wv = wl[p - NRG][tid];
                u32 hv = hq[q];
                a0 = dot2(wv.x, hv, a0);
                a1 = dot2(wv.y, hv, a1);
                a2 = dot2(wv.z, hv, a2);
                a3 = dot2(wv.w, hv, a3);
            }
        }

        if (kh == 1) {
            float4 r4; r4.x = a0; r4.y = a1; r4.z = a2; r4.w = a3;
            red[j] = r4;
        }
        __syncthreads();   // partials visible; all hv reads of step done
        if (kh == 0) {
            float4 r4 = red[j];
            a0 += r4.x; a1 += r4.y; a2 += r4.z; a3 += r4.w;
            float i_ = sigm(a0);
            float f_ = sigm(a1);
            float g_ = tanh_(a2);
            float o_ = sigm(a3);
            c = f_ * c + i_ * g_;
            float hn = o_ * tanh_(c);
            h = hn;
            hfh[j] = (_Float16)hn;
            if (houth) hoh[ho] = f2h(hn);
            else       __builtin_nontemporal_store(hn, hof + ho);
            ho += H_;
        }
        __syncthreads();   // new h visible
    }

    if (kh == 0) {
        J.state[b * H_ + j] = h;
        J.state[B_ * H_ + b * H_ + j] = c;
        if (J.hc_last) {
            J.hc_last[b * H_ + j] = h;
            J.hc_last[B_ * H_ + b * H_ + j] = c;
        }
    }
}

extern "C" void kernel_launch(void* const* d_in, const int* in_sizes, int n_in,
                              void* d_out, int out_size, void* d_ws, size_t ws_size,
                              hipStream_t stream)
{
    (void)in_sizes; (void)n_in; (void)out_size;

    const float* x    = (const float*)d_in[0];
    const float* Wih0 = (const float*)d_in[1];
    const float* Whh0 = (const float*)d_in[2];
    const float* b0   = (const float*)d_in[3];
    const float* Wih1 = (const float*)d_in[4];
    const float* Whh1 = (const float*)d_in[5];
    const float* b1   = (const float*)d_in[6];

    float* out   = (float*)d_out;
    float* hlast = out + (size_t)B_ * T_ * H_;

    // ws layout
    char* ws = (char*)d_ws;
    const size_t WPB  = (size_t)128 * 256 * 16;     // 524288 per packed W_hh
    const size_t WIHB = (size_t)1024 * 256 * 2;     // 524288 per f16 W_ih
    const size_t STB  = (size_t)2 * B_ * H_ * 4;    // 131072 per-layer state
    uint4* Wp0    = (uint4*)(ws);
    uint4* Wp1    = (uint4*)(ws + WPB);
    u16*   Wih0h  = (u16*)(ws + 2 * WPB);
    u16*   Wih1h  = (u16*)(ws + 2 * WPB + WIHB);
    float* state0 = (float*)(ws + 2 * WPB + 2 * WIHB);
    float* state1 = (float*)(ws + 2 * WPB + 2 * WIHB + STB);
    const size_t BASE = 2 * WPB + 2 * WIHB + 2 * STB;   // 2359296

    // Tc: largest power-of-2 <= 256 whose buffers fit ws.
    // per-Tc bytes: h1c 64*256*2 + xgA/xgB 2*64*1024*2 = 294912
    int Tc = 16;
    for (int tc = 256; tc >= 16; tc >>= 1)
        if (BASE + (size_t)tc * 294912 <= ws_size) { Tc = tc; break; }
    const int nch    = T_ / Tc;
    const int tclog2 = 31 - __builtin_clz((unsigned)Tc);
    const size_t H1CB = (size_t)B_ * Tc * H_ * 2;
    const size_t XGB  = (size_t)B_ * Tc * G_ * 2;
    u16*      h1c = (u16*)(ws + BASE);
    _Float16* xgA = (_Float16*)(ws + BASE + H1CB);
    _Float16* xgB = (_Float16*)(ws + BASE + H1CB + XGB);

    pack_whh<<<dim3(128, 2), 256, 0, stream>>>(Whh0, Whh1, Wp0, Wp1);
    pack_wih<<<dim3(256, 2), 256, 0, stream>>>(Wih0, Wih1, Wih0h, Wih1h);

    const int gemmWG = (B_ * Tc) / 64;

    // prologue: xg for layer-0 chunk 0
    gemm_xg<0><<<gemmWG, 256, 0, stream>>>(x, Wih0h, (u16*)xgA, tclog2, T_, 0);

    for (int s = 0; s <= nch; ++s) {
        ScanJob JA = {}; JA.Tc = 0;
        ScanJob JB = {}; JB.Tc = 0;
        if (s < nch) {                      // layer 0, chunk s
            JA.xg = xgA;  JA.Wp = Wp0;  JA.bias = b0;  JA.state = state0;
            JA.h_out = h1c;  JA.hc_last = nullptr;
            JA.Tc = Tc;  JA.toff = 0;  JA.TS = Tc;  JA.houth = 1;
            JA.first = (s == 0);
        }
        if (s >= 1) {                       // layer 1, chunk s-1
            int c = s - 1;
            JB.xg = xgB;  JB.Wp = Wp1;  JB.bias = b1;  JB.state = state1;
            JB.h_out = out;  JB.hc_last = (c == nch - 1) ? hlast : nullptr;
            JB.Tc = Tc;  JB.toff = c * Tc;  JB.TS = T_;  JB.houth = 0;
            JB.first = (c == 0);
        }
        lstm_scan2<<<128, 512, 0, stream>>>(JA, JB);

        if (s + 1 < nch)                    // xg for layer-0 chunk s+1
            gemm_xg<0><<<gemmWG, 256, 0, stream>>>(
                x, Wih0h, (u16*)xgA, tclog2, T_, (s + 1) * Tc);
        if (s < nch)                        // xg for layer-1 chunk s (from h1c)
            gemm_xg<1><<<gemmWG, 256, 0, stream>>>(
                h1c, Wih1h, (u16*)xgB, tclog2, Tc, 0);
    }
}